// Round 8
// baseline (45.629 us; speedup 1.0000x reference)
//
#include <hip/hip_runtime.h>
#include <math.h>

constexpr int IN_C = 31;
constexpr int TOT  = 44;
constexpr int HW   = 256 * 256;
constexpr int NPIX = 4 * HW;
constexpr float SMIN = 0.001f, SMAX = 1000.0f;
constexpr float PI_F = 3.14159265358979323846f;

__device__ __forceinline__ float frcp(float v) { return __builtin_amdgcn_rcpf(v); }

// Post-GEMV pipeline for ONE pixel: m store, scales, Givens R, S = R^T D R,
// stage S into per-wave LDS (16KB) and flush coalesced. Wave-synchronous:
// stage instrs precede flush instrs in program order, single wave, no barrier.
__device__ __forceinline__ void finish_pixel(
    const float* __restrict__ acc,   // 44 encoder outputs for this pixel
    float4* __restrict__ wbuf4,      // per-wave LDS, 1024 float4 (16 KB)
    float* __restrict__ out,
    int pix, int lane, size_t flushbase4)
{
    // ---- m ----
    float4* mp = reinterpret_cast<float4*>(out + (size_t)pix * 8);
    mp[0] = make_float4(acc[0], acc[1], acc[2], acc[3]);
    mp[1] = make_float4(acc[4], acc[5], acc[6], acc[7]);

    // ---- sqrt scales (rcp instead of IEEE divide) ----
    float sq[8];
#pragma unroll
    for (int j = 0; j < 8; ++j) {
        const float sig = frcp(1.0f + __expf(-acc[8 + j]));
        const float s   = fmaf(SMAX - SMIN, sig, SMIN);
        sq[j] = __builtin_amdgcn_sqrtf(s);
    }

    // ---- R from Givens chain (identity const-folded by full unroll) ----
    float R[8][8];
#pragma unroll
    for (int i = 0; i < 8; ++i)
#pragma unroll
        for (int k = 0; k < 8; ++k) R[i][k] = (i == k) ? 1.0f : 0.0f;

    int cc = 0;
#pragma unroll
    for (int i = 0; i < 7; ++i) {
#pragma unroll
        for (int j = i + 1; j < 8; ++j) {
            const float wv = acc[16 + cc];
            // tanh(wv) = 1 - 2/(e^{2wv}+1), rcp-based; saturates correctly
            const float th = fmaf(-2.0f, frcp(__expf(2.0f * wv) + 1.0f), 1.0f);
            const float a  = PI_F * th;
            const float cs = __cosf(a);
            const float ss = __sinf(a);
#pragma unroll
            for (int r = 0; r < 8; ++r) {
                const float ri = R[r][i];
                const float rj = R[r][j];
                R[r][i] = fmaf(ri, cs, rj * ss);
                R[r][j] = fmaf(rj, cs, -(ri * ss));
            }
            ++cc;
        }
    }

    // scale row j by sqrt(s_j):  S = (sqrtD R)^T (sqrtD R)
#pragma unroll
    for (int j = 0; j < 8; ++j)
#pragma unroll
        for (int k = 0; k < 8; ++k) R[j][k] *= sq[j];

    float S[8][8];
#pragma unroll
    for (int i = 0; i < 8; ++i)
#pragma unroll
        for (int k = i; k < 8; ++k) {
            float d = 0.0f;
#pragma unroll
            for (int j = 0; j < 8; ++j) d = fmaf(R[j][i], R[j][k], d);
            S[i][k] = d; S[k][i] = d;
        }

    // ---- stage: lane's 16 float4s, swizzle v ^ (lane&15) (bank-clean) ----
#pragma unroll
    for (int i = 0; i < 8; ++i) {
        const int v0 = i * 2, v1 = v0 + 1;
        wbuf4[lane * 16 + (v0 ^ (lane & 15))] =
            make_float4(S[i][0], S[i][1], S[i][2], S[i][3]);
        wbuf4[lane * 16 + (v1 ^ (lane & 15))] =
            make_float4(S[i][4], S[i][5], S[i][6], S[i][7]);
    }

    // ---- flush: 16 iters x 64 lanes x 16B = 16KB contiguous ----
    float4* S4 = reinterpret_cast<float4*>(out + (size_t)NPIX * 8);
#pragma unroll
    for (int k = 0; k < 16; ++k) {
        const int t  = k * 64 + lane;
        const int pl = t >> 4;            // staging lane
        const int v  = t & 15;            // float4 index within pixel
        S4[flushbase4 + t] = wbuf4[pl * 16 + (v ^ (pl & 15))];
    }
}

// 2 pixels/thread: two independent dep-chains interleaved in the GEMV fill
// each other's stalls; each scalar weight batch feeds both pixels' FMAs.
// Grid 512 blocks = 2 blocks/CU co-resident (LDS 64KB x 2 <= 160KB).
__global__ __launch_bounds__(256, 2) void sepgpd_fused(
    const float* __restrict__ x,
    const float* __restrict__ Wenc,
    const float* __restrict__ benc,
    float* __restrict__ out)
{
    __shared__ float4 sbuf4[4][1024];    // 64 KB: 4 waves x 16 KB

    const int tid  = threadIdx.x;
    const int lane = tid & 63;
    const int wid  = tid >> 6;
    const int W0   = blockIdx.x * 512 + wid * 128;  // wave's first pixel
    const int pA   = W0 + lane;
    const int pB   = pA + 64;
    const int b    = pA >> 16;                      // 512 | 65536: same image
    const int hwA  = pA & (HW - 1);

    const float* xp = x + (size_t)b * IN_C * HW + hwA;

    // ---- x for both pixels: 62 coalesced loads ----
    float xA[IN_C], xB[IN_C];
#pragma unroll
    for (int c = 0; c < IN_C; ++c) {
        xA[c] = xp[(size_t)c * HW];
        xB[c] = xp[(size_t)c * HW + 64];
    }

    // ---- dual GEMV: weight row read once (contiguous -> s_load batches) ----
    float aA[TOT], aB[TOT];
#pragma unroll
    for (int o = 0; o < TOT; ++o) {
        float sA = benc[o], sB = sA;
#pragma unroll
        for (int c = 0; c < IN_C; ++c) {
            const float w = Wenc[o * IN_C + c];
            sA = fmaf(xA[c], w, sA);
            sB = fmaf(xB[c], w, sB);
        }
        aA[o] = sA; aB[o] = sB;
    }

    float4* wbuf4 = &sbuf4[wid][0];
    finish_pixel(aA, wbuf4, out, pA, lane, (size_t)W0 * 16);
    finish_pixel(aB, wbuf4, out, pB, lane, (size_t)(W0 + 64) * 16);
}

extern "C" void kernel_launch(void* const* d_in, const int* in_sizes, int n_in,
                              void* d_out, int out_size, void* d_ws, size_t ws_size,
                              hipStream_t stream)
{
    const float* x    = (const float*)d_in[0];
    const float* Wenc = (const float*)d_in[1];
    const float* benc = (const float*)d_in[2];
    float* out        = (float*)d_out;

    dim3 grid(NPIX / 512), block(256);
    sepgpd_fused<<<grid, block, 0, stream>>>(x, Wenc, benc, out);
}